// Round 14
// baseline (3289.704 us; speedup 1.0000x reference)
//
#include <hip/hip_runtime.h>
#include <hip/hip_bf16.h>

typedef __bf16 bf16x8 __attribute__((ext_vector_type(8)));
typedef __bf16 bf16x4 __attribute__((ext_vector_type(4)));
typedef float  f32x4  __attribute__((ext_vector_type(4)));
typedef unsigned int u32;
typedef unsigned long long u64;

// ---- inline-asm MFMA with B operand in AGPR (proven R7/R13) --------------
static __device__ __forceinline__ void mfma_z(f32x4& d, bf16x8 a, const f32x4& b) {
    asm("v_mfma_f32_16x16x32_bf16 %0, %1, %2, 0"
        : "=&v"(d) : "v"(a), "a"(b));
}
static __device__ __forceinline__ void mfma_a(f32x4& d, bf16x8 a, const f32x4& b) {
    asm("v_mfma_f32_16x16x32_bf16 %0, %1, %2, %0"
        : "+v"(d) : "v"(a), "a"(b));
}
#define ACC_GUARD(e, o) asm volatile("s_nop 7\n\ts_nop 7" : "+v"(e), "+v"(o))

static __device__ __forceinline__ f32x4 mfma16(bf16x8 a, bf16x8 b, f32x4 c) {
    return __builtin_amdgcn_mfma_f32_16x16x32_bf16(a, b, c, 0, 0, 0);
}

// Bounded spin + give-up latch (protocol failure -> fast absmax FAIL, no hang)
static __device__ __forceinline__ void poll_flags(const u32* flags, u32 tgt,
                                                  int lane, u32& alive) {
    if (!alive) return;
    for (u32 it = 0; it < (1u << 20); ++it) {
        u32 v = __hip_atomic_load(&flags[lane & 7], __ATOMIC_RELAXED, __HIP_MEMORY_SCOPE_AGENT);
        if (__all((int)(v >= tgt))) return;
        __builtin_amdgcn_s_sleep(1);
    }
    alive = 0;
}

#define TLEN 512
#define IDIM 128
#define FDIM 512
#define MDIM 512
#define ODIM 128
#define BC   16
#define BCS  8       // rows per stream (2 streams per group)
#define NGRP 16
#define NCU  8
#define PSTR 520
#define XSTR 136
#define BUFBLK (2*BCS*MDIM)   // 8192 elems per (parity,group,stream)

// ---- ws byte offsets ----
#define WS_WI   0
#define WS_W2F  (WS_WI  + FDIM*IDIM*2)
#define WS_W2M  (WS_W2F + FDIM*MDIM*2)
#define WS_WF2  (WS_W2M + MDIM*MDIM*2)
#define WS_WO   (WS_WF2 + MDIM*FDIM*2)
#define WS_C    (WS_WO  + ODIM*MDIM*2)
#define WS_D    (WS_C   + FDIM*FDIM*2)
#define WS_B1   (WS_D   + MDIM*FDIM*2)
#define WS_B23  (WS_B1  + FDIM*4)
#define WS_CB   (WS_B23 + MDIM*4)
#define WS_CU   (WS_CB  + FDIM*4)
#define WS_FLG  (WS_CU  + MDIM*4)
#define WS_BUF  (WS_FLG + NGRP*64*4)     // bf16 [2][NGRP][2][2][8][512] = 1MB

#define N_WI  (FDIM*IDIM)
#define N_W2F (FDIM*MDIM)
#define N_W2M (MDIM*MDIM)
#define N_WF2 (MDIM*FDIM)
#define N_WO  (ODIM*MDIM)

__global__ __launch_bounds__(256) void lmn_prep1(
    const float* __restrict__ Wi2f, const float* __restrict__ Wm2f,
    const float* __restrict__ Wm2m, const float* __restrict__ Wf2m,
    const float* __restrict__ Wout,
    const float* __restrict__ bi2f, const float* __restrict__ bm2f,
    const float* __restrict__ bf2m, const float* __restrict__ bm2m,
    __bf16* __restrict__ WI, __bf16* __restrict__ W2F, __bf16* __restrict__ W2M,
    __bf16* __restrict__ WF2, __bf16* __restrict__ WO,
    float* __restrict__ b1, float* __restrict__ b23, u32* __restrict__ flags)
{
    int i = blockIdx.x * 256 + threadIdx.x;
    if (i < N_WI)  { WI[i]  = (__bf16)Wi2f[i]; return; }  i -= N_WI;
    if (i < N_W2F) { W2F[i] = (__bf16)Wm2f[i]; return; }  i -= N_W2F;
    if (i < N_W2M) { W2M[i] = (__bf16)Wm2m[i]; return; }  i -= N_W2M;
    if (i < N_WF2) { WF2[i] = (__bf16)Wf2m[i]; return; }  i -= N_WF2;
    if (i < N_WO)  { WO[i]  = (__bf16)Wout[i]; return; }  i -= N_WO;
    if (i < FDIM)  { b1[i]  = bi2f[i] + bm2f[i]; return; } i -= FDIM;
    if (i < MDIM)  { b23[i] = bf2m[i] + bm2m[i]; return; } i -= MDIM;
    if (i < NGRP * 64) { flags[i] = 0u; return; }
}

// Composites: C = Wm2f@Wf2m, D = Wm2m@Wf2m, cb = b1 + Wm2f@b23, cu = Wm2m@b23
__global__ __launch_bounds__(256) void lmn_prep2(
    const float* __restrict__ Wm2f, const float* __restrict__ Wm2m,
    const float* __restrict__ Wf2m,
    const float* __restrict__ b1, const float* __restrict__ b23,
    __bf16* __restrict__ C, __bf16* __restrict__ D,
    float* __restrict__ cb, float* __restrict__ cu)
{
    int bb = blockIdx.x;
    if (bb < 2048) {
        int row = bb >> 1;
        int k   = (bb & 1) * 256 + threadIdx.x;
        const float* A = (row < 512) ? Wm2f : Wm2m;
        int r = row & 511;
        float acc = 0.f;
        for (int j = 0; j < 512; ++j)
            acc += A[(size_t)r * 512 + j] * Wf2m[(size_t)j * 512 + k];
        if (row < 512) C[(size_t)r * 512 + k] = (__bf16)acc;
        else           D[(size_t)r * 512 + k] = (__bf16)acc;
        return;
    }
    int idx = (bb - 2048) * 256 + threadIdx.x;
    if (idx < 512) {
        float acc = b1[idx];
        for (int j = 0; j < 512; ++j) acc += Wm2f[(size_t)idx * 512 + j] * b23[j];
        cb[idx] = acc;
    } else {
        int r = idx - 512;
        float acc = 0.f;
        for (int j = 0; j < 512; ++j) acc += Wm2m[(size_t)r * 512 + j] * b23[j];
        cu[r] = acc;
    }
}

// ---------------------------------------------------------------------------
// R13 state-transformed scan + DUAL-STREAM latency hiding: each group's 16
// rows = two independent 8-row streams sharing the same AGPR weights. The
// loop interleaves half-iterations; stream A's flag->poll RTT hides under
// stream B's full half (gather+MFMA+stage+export) and vice versa. 8-row
// MFMA tiles (lanes 8-15 read duplicated rows; outputs unused). u/f staged
// via sstg so stage-writes never race gathered-LDS reads (3 barriers/half).
// Overwrite gating inductive per stream as R13 (gather(t) precedes
// export(t+1)/flag(t+2) in program order; parity double-buffer).
// ---------------------------------------------------------------------------
__global__ __launch_bounds__(512, 2) void lmn_scan(
    const float* __restrict__ x, const float* __restrict__ m0,
    const __bf16* __restrict__ WI, const __bf16* __restrict__ W2F,
    const __bf16* __restrict__ W2M, const __bf16* __restrict__ Cm,
    const __bf16* __restrict__ Dm, const __bf16* __restrict__ WF2,
    const __bf16* __restrict__ WO,
    const float* __restrict__ b1, const float* __restrict__ cb,
    const float* __restrict__ cu, const float* __restrict__ b23,
    const float* __restrict__ bout,
    u32* __restrict__ flags_all, __bf16* __restrict__ buf,
    float* __restrict__ out)
{
    __shared__ __bf16 ulds[2][BCS][PSTR];
    __shared__ __bf16 flds[2][BCS][PSTR];
    __shared__ __bf16 xlds[2][BCS][XSTR];
    __shared__ __bf16 sstg[2][2][BCS][72];    // [stream][mat 0=u,1=f][row][col]

    const int tid  = threadIdx.x;
    const int lane = tid & 63;
    const int w    = tid >> 6;
    const int wq   = w & 3;
    const int l15  = lane & 15;
    const int l4   = lane >> 4;
    const int koff = 8 * l4;
    const int ar   = l15 & 7;                 // A-frag row in 8-row tile
    const bool sRole = (w < 4);

    const int b = blockIdx.x;
    const int g = b & 15;
    const int p = b >> 4;
    const int row0 = g * BC;

    u32* flagS0 = flags_all + g * 64 + 16;    // stream 0 flags [8]
    u32* flagS1 = flags_all + g * 64 + 24;    // stream 1 flags [8]
    u32  alive = 1;

    const int c0 = 64 * p + 16 * wq + l15;

    // ---- resident weights -> AGPRs (36 frags = 144 AGPR max; R13) ----
    f32x4 wgt[36];
    {
        const __bf16* rA = (sRole ? W2F : W2M) + (size_t)c0 * MDIM;
        const __bf16* rC = (sRole ? Cm  : Dm ) + (size_t)c0 * FDIM;
        #pragma unroll
        for (int j = 0; j < 16; ++j) {
            wgt[j]      = *(const f32x4*)&rA[j * 32 + koff];
            wgt[16 + j] = *(const f32x4*)&rC[j * 32 + koff];
        }
        if (sRole) {
            const __bf16* rX = WI + (size_t)c0 * IDIM;
            #pragma unroll
            for (int j = 0; j < 4; ++j) wgt[32 + j] = *(const f32x4*)&rX[j * 32 + koff];
        } else {
            #pragma unroll
            for (int j = 32; j < 36; ++j) wgt[j] = f32x4{0, 0, 0, 0};
        }
        #pragma unroll
        for (int j = 0; j < 36; ++j) asm volatile("" : "+a"(wgt[j]));
    }
    const float b1r = sRole ? b1[c0] : 0.f;
    const float cbr = sRole ? cb[c0] : 0.f;
    const float cur = sRole ? 0.f    : cu[c0];

    // ================= prologue: epoch 0 for both streams =================
    #pragma unroll
    for (int s = 0; s < 2; ++s) {
        {   // m0 rows (8 x 512) -> ulds[s]
            int row = tid >> 6, col8 = (tid & 63) << 3;
            const float* ms = &m0[(size_t)(row0 + 8 * s + row) * MDIM + col8];
            float4 v0 = ((const float4*)ms)[0], v1 = ((const float4*)ms)[1];
            *(bf16x8*)&ulds[s][row][col8] =
                bf16x8{(__bf16)v0.x, (__bf16)v0.y, (__bf16)v0.z, (__bf16)v0.w,
                       (__bf16)v1.x, (__bf16)v1.y, (__bf16)v1.z, (__bf16)v1.w};
        }
        if (tid < 128) {   // x_0 -> xlds[s]
            int rr = tid >> 4, c8 = (tid & 15) << 3;
            const float* xs = &x[(size_t)(row0 + 8 * s + rr) * TLEN * IDIM + c8];
            float4 v0 = ((const float4*)xs)[0], v1 = ((const float4*)xs)[1];
            *(bf16x8*)&xlds[s][rr][c8] =
                bf16x8{(__bf16)v0.x, (__bf16)v0.y, (__bf16)v0.z, (__bf16)v0.w,
                       (__bf16)v1.x, (__bf16)v1.y, (__bf16)v1.z, (__bf16)v1.w};
        }
        __syncthreads();
        f32x4 accE, accO;
        {
            bf16x8 a0 = *(const bf16x8*)&ulds[s][ar][0 * 32 + koff];
            bf16x8 a1 = *(const bf16x8*)&ulds[s][ar][1 * 32 + koff];
            mfma_z(accE, a0, wgt[0]);  mfma_z(accO, a1, wgt[1]);
            #pragma unroll
            for (int j = 2; j < 16; ++j) {
                bf16x8 am = *(const bf16x8*)&ulds[s][ar][j * 32 + koff];
                if (j & 1) mfma_a(accO, am, wgt[j]);
                else       mfma_a(accE, am, wgt[j]);
            }
            if (sRole) {
                #pragma unroll
                for (int j = 0; j < 4; ++j) {
                    bf16x8 ax = *(const bf16x8*)&xlds[s][ar][j * 32 + koff];
                    if (j & 1) mfma_a(accO, ax, wgt[32 + j]);
                    else       mfma_a(accE, ax, wgt[32 + j]);
                }
            }
        }
        ACC_GUARD(accE, accO);
        f32x4 va = accE + accO;
        {
            int mat = sRole ? 1 : 0;
            #pragma unroll
            for (int r = 0; r < 4; ++r) {
                int rr = 4 * l4 + r;
                if (rr < 8)
                    sstg[s][mat][rr][16 * wq + l15] =
                        sRole ? (__bf16)tanhf(va[r] + b1r) : (__bf16)va[r];
            }
        }
        __syncthreads();
        if (tid < 256) {   // export epoch 0 -> parity 0
            int mat = tid >> 7, idx = tid & 127;
            int rr = idx >> 4, c4 = (idx & 15) << 2;
            u64 v = *(const u64*)&sstg[s][mat][rr][c4];
            __bf16* dst = buf + ((size_t)(0 * NGRP + g) * 2 + s) * BUFBLK
                        + (size_t)mat * (BCS * MDIM) + rr * MDIM + 64 * p + c4;
            __hip_atomic_store((u64*)dst, v, __ATOMIC_RELAXED, __HIP_MEMORY_SCOPE_AGENT);
        }
        if (tid < 128) {   // stage x_1
            int rr = tid >> 4, c8 = (tid & 15) << 3;
            const float* xs = &x[((size_t)(row0 + 8 * s + rr) * TLEN + 1) * IDIM + c8];
            float4 v0 = ((const float4*)xs)[0], v1 = ((const float4*)xs)[1];
            *(bf16x8*)&xlds[s][rr][c8] =
                bf16x8{(__bf16)v0.x, (__bf16)v0.y, (__bf16)v0.z, (__bf16)v0.w,
                       (__bf16)v1.x, (__bf16)v1.y, (__bf16)v1.z, (__bf16)v1.w};
        }
        asm volatile("s_waitcnt vmcnt(0)" ::: "memory");
        __syncthreads();
        if (tid == 0)
            __hip_atomic_store((s ? flagS1 : flagS0) + p, 1u,
                               __ATOMIC_RELAXED, __HIP_MEMORY_SCOPE_AGENT);
    }

    // ================= main loop: interleaved half-iterations =============
    for (int t = 0; t < TLEN; ++t) {
        const int gpar = t & 1, epar = (t + 1) & 1;
        #pragma unroll
        for (int s = 0; s < 2; ++s) {
            u32* flg = s ? flagS1 : flagS0;
            poll_flags(flg, (u32)t + 1u, lane, alive);
            // gather epoch t (16 KB coalesced)
            const __bf16* gbase = buf + ((size_t)(gpar * NGRP + g) * 2 + s) * BUFBLK;
            #pragma unroll
            for (int i = 0; i < 2; ++i) {
                int c = tid + 512 * i;
                int mat = c >> 9, rem = c & 511;
                int row = rem >> 6, col8 = (rem & 63) << 3;
                const __bf16* src = gbase + (size_t)mat * (BCS * MDIM) + row * MDIM + col8;
                u64 lo = __hip_atomic_load((const u64*)src,     __ATOMIC_RELAXED, __HIP_MEMORY_SCOPE_AGENT);
                u64 hi = __hip_atomic_load((const u64*)src + 1, __ATOMIC_RELAXED, __HIP_MEMORY_SCOPE_AGENT);
                union { u64 q[2]; bf16x8 v; } uu; uu.q[0] = lo; uu.q[1] = hi;
                if (mat) *(bf16x8*)&flds[s][row][col8] = uu.v;
                else     *(bf16x8*)&ulds[s][row][col8] = uu.v;
            }
            __syncthreads();          // bar1: epoch-t (u,f) in LDS
            if (t < TLEN - 1) {
                f32x4 accE, accO;
                bf16x8 a0 = *(const bf16x8*)&ulds[s][ar][0 * 32 + koff];
                bf16x8 a1 = *(const bf16x8*)&ulds[s][ar][1 * 32 + koff];
                mfma_z(accE, a0, wgt[0]);  mfma_z(accO, a1, wgt[1]);
                #pragma unroll
                for (int j = 2; j < 16; ++j) {
                    bf16x8 am = *(const bf16x8*)&ulds[s][ar][j * 32 + koff];
                    if (j & 1) mfma_a(accO, am, wgt[j]);
                    else       mfma_a(accE, am, wgt[j]);
                }
                #pragma unroll
                for (int j = 0; j < 16; ++j) {
                    bf16x8 af = *(const bf16x8*)&flds[s][ar][j * 32 + koff];
                    if (j & 1) mfma_a(accO, af, wgt[16 + j]);
                    else       mfma_a(accE, af, wgt[16 + j]);
                }
                if (sRole) {
                    #pragma unroll
                    for (int j = 0; j < 4; ++j) {
                        bf16x8 ax = *(const bf16x8*)&xlds[s][ar][j * 32 + koff];
                        if (j & 1) mfma_a(accO, ax, wgt[32 + j]);
                        else       mfma_a(accE, ax, wgt[32 + j]);
                    }
                }
                ACC_GUARD(accE, accO);
                f32x4 va = accE + accO;
                int mat = sRole ? 1 : 0;
                #pragma unroll
                for (int r = 0; r < 4; ++r) {
                    int rr = 4 * l4 + r;
                    if (rr < 8)
                        sstg[s][mat][rr][16 * wq + l15] =
                            sRole ? (__bf16)tanhf(va[r] + cbr) : (__bf16)(va[r] + cur);
                }
            }
            __syncthreads();          // bar2: sstg staged; xlds/MFMA reads done
            if (t < TLEN - 1) {
                if (tid < 256) {      // export epoch t+1 -> parity epar
                    int mat = tid >> 7, idx = tid & 127;
                    int rr = idx >> 4, c4 = (idx & 15) << 2;
                    u64 v = *(const u64*)&sstg[s][mat][rr][c4];
                    __bf16* dst = buf + ((size_t)(epar * NGRP + g) * 2 + s) * BUFBLK
                                + (size_t)mat * (BCS * MDIM) + rr * MDIM + 64 * p + c4;
                    __hip_atomic_store((u64*)dst, v, __ATOMIC_RELAXED, __HIP_MEMORY_SCOPE_AGENT);
                }
                if (tid < 128 && t + 2 < TLEN) {   // stage x_{t+2}
                    int rr = tid >> 4, c8 = (tid & 15) << 3;
                    const float* xs = &x[((size_t)(row0 + 8 * s + rr) * TLEN + (t + 2)) * IDIM + c8];
                    float4 v0 = ((const float4*)xs)[0], v1 = ((const float4*)xs)[1];
                    *(bf16x8*)&xlds[s][rr][c8] =
                        bf16x8{(__bf16)v0.x, (__bf16)v0.y, (__bf16)v0.z, (__bf16)v0.w,
                               (__bf16)v1.x, (__bf16)v1.y, (__bf16)v1.z, (__bf16)v1.w};
                }
            }
            asm volatile("s_waitcnt vmcnt(0)" ::: "memory");
            __syncthreads();          // bar3: exports drained
            if (t < TLEN - 1 && tid == 0)
                __hip_atomic_store(flg + p, (u32)t + 2u,
                                   __ATOMIC_RELAXED, __HIP_MEMORY_SCOPE_AGENT);
        }
    }

    // ============ epilogue (p==0): m_T = u + f@WF2^T + b23; out ============
    __syncthreads();
    if (p == 0) {
        #pragma unroll
        for (int s = 0; s < 2; ++s) {
            f32x4 ma[4];
            #pragma unroll
            for (int nt = 0; nt < 4; ++nt) {
                int ct = 64 * w + 16 * nt + l15;
                f32x4 acc = {0, 0, 0, 0};
                #pragma unroll
                for (int j = 0; j < 16; ++j) {
                    bf16x8 af = *(const bf16x8*)&flds[s][ar][j * 32 + koff];
                    bf16x8 bw = *(const bf16x8*)&WF2[(size_t)ct * FDIM + j * 32 + koff];
                    acc = mfma16(af, bw, acc);
                }
                ma[nt] = acc;
            }
            #pragma unroll
            for (int nt = 0; nt < 4; ++nt) {
                int ct = 64 * w + 16 * nt + l15;
                #pragma unroll
                for (int r = 0; r < 4; ++r) {
                    int rr = 4 * l4 + r;
                    if (rr < 8) {
                        float mv = ma[nt][r] + (float)ulds[s][rr][ct] + b23[ct];
                        ulds[s][rr][ct] = (__bf16)mv;
                    }
                }
            }
            __syncthreads();
            const int oc = 16 * w + l15;
            const __bf16* ro = WO + (size_t)oc * MDIM;
            f32x4 oe = {0, 0, 0, 0}, oo = {0, 0, 0, 0};
            #pragma unroll
            for (int j = 0; j < 16; ++j) {
                bf16x8 am = *(const bf16x8*)&ulds[s][ar][j * 32 + koff];
                bf16x8 bw = *(const bf16x8*)&ro[j * 32 + koff];
                if (j & 1) oo = mfma16(am, bw, oo); else oe = mfma16(am, bw, oe);
            }
            f32x4 oa = oe + oo;
            const float bo = bout[oc];
            #pragma unroll
            for (int r = 0; r < 4; ++r) {
                int rr = 4 * l4 + r;
                if (rr < 8)
                    out[(size_t)(row0 + 8 * s + rr) * ODIM + oc] = oa[r] + bo;
            }
            __syncthreads();
        }
    }
}

extern "C" void kernel_launch(void* const* d_in, const int* in_sizes, int n_in,
                              void* d_out, int out_size, void* d_ws, size_t ws_size,
                              hipStream_t stream)
{
    const float* x    = (const float*)d_in[0];
    const float* m0   = (const float*)d_in[1];
    const float* Wi2f = (const float*)d_in[2];
    const float* bi2f = (const float*)d_in[3];
    const float* Wm2f = (const float*)d_in[4];
    const float* bm2f = (const float*)d_in[5];
    const float* Wf2m = (const float*)d_in[6];
    const float* bf2m = (const float*)d_in[7];
    const float* Wm2m = (const float*)d_in[8];
    const float* bm2m = (const float*)d_in[9];
    const float* Wout = (const float*)d_in[10];
    const float* bout = (const float*)d_in[11];

    char* ws = (char*)d_ws;
    __bf16* WI  = (__bf16*)(ws + WS_WI);
    __bf16* W2F = (__bf16*)(ws + WS_W2F);
    __bf16* W2M = (__bf16*)(ws + WS_W2M);
    __bf16* WF2 = (__bf16*)(ws + WS_WF2);
    __bf16* WO  = (__bf16*)(ws + WS_WO);
    __bf16* Cm  = (__bf16*)(ws + WS_C);
    __bf16* Dm  = (__bf16*)(ws + WS_D);
    float*  b1  = (float*)(ws + WS_B1);
    float*  b23 = (float*)(ws + WS_B23);
    float*  cb  = (float*)(ws + WS_CB);
    float*  cu  = (float*)(ws + WS_CU);
    u32*    flg = (u32*)(ws + WS_FLG);
    __bf16* buf = (__bf16*)(ws + WS_BUF);

    const int prep1_total = N_WI + N_W2F + N_W2M + N_WF2 + N_WO
                          + FDIM + MDIM + NGRP * 64;
    lmn_prep1<<<(prep1_total + 255) / 256, 256, 0, stream>>>(
        Wi2f, Wm2f, Wm2m, Wf2m, Wout, bi2f, bm2f, bf2m, bm2m,
        WI, W2F, W2M, WF2, WO, b1, b23, flg);

    lmn_prep2<<<2052, 256, 0, stream>>>(Wm2f, Wm2m, Wf2m, b1, b23, Cm, Dm, cb, cu);

    lmn_scan<<<NGRP * NCU, 512, 0, stream>>>(
        x, m0, WI, W2F, W2M, Cm, Dm, WF2, WO,
        b1, cb, cu, b23, bout, flg, buf, (float*)d_out);
}

// Round 15
// 1853.372 us; speedup vs baseline: 1.7750x; 1.7750x over previous
//
#include <hip/hip_runtime.h>
#include <hip/hip_bf16.h>

typedef __bf16 bf16x8 __attribute__((ext_vector_type(8)));
typedef __bf16 bf16x4 __attribute__((ext_vector_type(4)));
typedef float  f32x4  __attribute__((ext_vector_type(4)));
typedef unsigned int u32;
typedef unsigned long long u64;

// ---- inline-asm MFMA with B operand in AGPR (proven R7/R13) --------------
static __device__ __forceinline__ void mfma_z(f32x4& d, bf16x8 a, const f32x4& b) {
    asm("v_mfma_f32_16x16x32_bf16 %0, %1, %2, 0"
        : "=&v"(d) : "v"(a), "a"(b));
}
static __device__ __forceinline__ void mfma_a(f32x4& d, bf16x8 a, const f32x4& b) {
    asm("v_mfma_f32_16x16x32_bf16 %0, %1, %2, %0"
        : "+v"(d) : "v"(a), "a"(b));
}
#define ACC_GUARD(e, o) asm volatile("s_nop 7\n\ts_nop 7" : "+v"(e), "+v"(o))

static __device__ __forceinline__ f32x4 mfma16(bf16x8 a, bf16x8 b, f32x4 c) {
    return __builtin_amdgcn_mfma_f32_16x16x32_bf16(a, b, c, 0, 0, 0);
}

// Tight bounded spin + give-up latch (no s_sleep quantization).
// Protocol failure -> fast absmax FAIL, never a hang (~<1 s worst case).
static __device__ __forceinline__ void poll_flags(const u32* flags, u32 tgt,
                                                  int lane, u32& alive) {
    if (!alive) return;
    for (u32 it = 0; it < (1u << 22); ++it) {
        u32 v = __hip_atomic_load(&flags[lane & 7], __ATOMIC_RELAXED, __HIP_MEMORY_SCOPE_AGENT);
        if (__all((int)(v >= tgt))) return;
    }
    alive = 0;
}

#define TLEN 512
#define IDIM 128
#define FDIM 512
#define MDIM 512
#define ODIM 128
#define BC   16
#define NGRP 16
#define NCU  8
#define PSTR 520
#define XSTR 136
#define SSTR 20      // sstg row stride (40B -> 8B-aligned u64 reads)

// ---- ws byte offsets ----
#define WS_WI   0                               // bf16 [512][128]
#define WS_W2F  (WS_WI  + FDIM*IDIM*2)          // bf16 [512][512] (Wm2f)
#define WS_W2M  (WS_W2F + FDIM*MDIM*2)          // bf16 [512][512] (Wm2m)
#define WS_WF2  (WS_W2M + MDIM*MDIM*2)          // bf16 [512][512] (Wf2m)
#define WS_WO   (WS_WF2 + MDIM*FDIM*2)          // bf16 [128][512]
#define WS_C    (WS_WO  + ODIM*MDIM*2)          // bf16 [512][512] = Wm2f@Wf2m
#define WS_D    (WS_C   + FDIM*FDIM*2)          // bf16 [512][512] = Wm2m@Wf2m
#define WS_B1   (WS_D   + MDIM*FDIM*2)          // f32 512
#define WS_B23  (WS_B1  + FDIM*4)               // f32 512
#define WS_CB   (WS_B23 + MDIM*4)               // f32 512: b1 + Wm2f@b23
#define WS_CU   (WS_CB  + FDIM*4)               // f32 512: Wm2m@b23
#define WS_FLG  (WS_CU  + MDIM*4)               // u32 [NGRP][64]
#define WS_BUF  (WS_FLG + NGRP*64*4)            // bf16 [2][NGRP][2][16][512] = 1MB

#define N_WI  (FDIM*IDIM)
#define N_W2F (FDIM*MDIM)
#define N_W2M (MDIM*MDIM)
#define N_WF2 (MDIM*FDIM)
#define N_WO  (ODIM*MDIM)

__global__ __launch_bounds__(256) void lmn_prep1(
    const float* __restrict__ Wi2f, const float* __restrict__ Wm2f,
    const float* __restrict__ Wm2m, const float* __restrict__ Wf2m,
    const float* __restrict__ Wout,
    const float* __restrict__ bi2f, const float* __restrict__ bm2f,
    const float* __restrict__ bf2m, const float* __restrict__ bm2m,
    __bf16* __restrict__ WI, __bf16* __restrict__ W2F, __bf16* __restrict__ W2M,
    __bf16* __restrict__ WF2, __bf16* __restrict__ WO,
    float* __restrict__ b1, float* __restrict__ b23, u32* __restrict__ flags)
{
    int i = blockIdx.x * 256 + threadIdx.x;
    if (i < N_WI)  { WI[i]  = (__bf16)Wi2f[i]; return; }  i -= N_WI;
    if (i < N_W2F) { W2F[i] = (__bf16)Wm2f[i]; return; }  i -= N_W2F;
    if (i < N_W2M) { W2M[i] = (__bf16)Wm2m[i]; return; }  i -= N_W2M;
    if (i < N_WF2) { WF2[i] = (__bf16)Wf2m[i]; return; }  i -= N_WF2;
    if (i < N_WO)  { WO[i]  = (__bf16)Wout[i]; return; }  i -= N_WO;
    if (i < FDIM)  { b1[i]  = bi2f[i] + bm2f[i]; return; } i -= FDIM;
    if (i < MDIM)  { b23[i] = bf2m[i] + bm2m[i]; return; } i -= MDIM;
    if (i < NGRP * 64) { flags[i] = 0u; return; }
}

// Composites: C = Wm2f@Wf2m, D = Wm2m@Wf2m, cb = b1 + Wm2f@b23, cu = Wm2m@b23
__global__ __launch_bounds__(256) void lmn_prep2(
    const float* __restrict__ Wm2f, const float* __restrict__ Wm2m,
    const float* __restrict__ Wf2m,
    const float* __restrict__ b1, const float* __restrict__ b23,
    __bf16* __restrict__ C, __bf16* __restrict__ D,
    float* __restrict__ cb, float* __restrict__ cu)
{
    int bb = blockIdx.x;
    if (bb < 2048) {
        int row = bb >> 1;
        int k   = (bb & 1) * 256 + threadIdx.x;
        const float* A = (row < 512) ? Wm2f : Wm2m;
        int r = row & 511;
        float acc = 0.f;
        for (int j = 0; j < 512; ++j)
            acc += A[(size_t)r * 512 + j] * Wf2m[(size_t)j * 512 + k];
        if (row < 512) C[(size_t)r * 512 + k] = (__bf16)acc;
        else           D[(size_t)r * 512 + k] = (__bf16)acc;
        return;
    }
    int idx = (bb - 2048) * 256 + threadIdx.x;
    if (idx < 512) {
        float acc = b1[idx];
        for (int j = 0; j < 512; ++j) acc += Wm2f[(size_t)idx * 512 + j] * b23[j];
        cb[idx] = acc;
    } else {
        int r = idx - 512;
        float acc = 0.f;
        for (int j = 0; j < 512; ++j) acc += Wm2m[(size_t)r * 512 + j] * b23[j];
        cu[r] = acc;
    }
}

// ---------------------------------------------------------------------------
// R13 state-transformed scan with a shortened per-step chain:
//   - bar0 removed (proven redundant: all LDS write/read pairs span barA/barB)
//   - bar1 removed via SAME-WAVE stage->export (each wave stages its own
//     16-col slice into a private sstg block, lgkmcnt(0), exports 1 u64/lane)
//   - tight polls (no s_sleep)
// 2 barriers/step (was 4). Protocol/overwrite gating identical to R13:
// flag(t+1) follows gather(t-1) in program order; parity double-buffer.
// ---------------------------------------------------------------------------
__global__ __launch_bounds__(512, 2) void lmn_scan(
    const float* __restrict__ x, const float* __restrict__ m0,
    const __bf16* __restrict__ WI, const __bf16* __restrict__ W2F,
    const __bf16* __restrict__ W2M, const __bf16* __restrict__ Cm,
    const __bf16* __restrict__ Dm, const __bf16* __restrict__ WF2,
    const __bf16* __restrict__ WO,
    const float* __restrict__ b1, const float* __restrict__ cb,
    const float* __restrict__ cu, const float* __restrict__ b23,
    const float* __restrict__ bout,
    u32* __restrict__ flags_all, __bf16* __restrict__ buf,
    float* __restrict__ out)
{
    __shared__ __bf16 ulds[BC][PSTR];
    __shared__ __bf16 flds[BC][PSTR];
    __shared__ __bf16 xlds[BC][XSTR];
    __shared__ __bf16 sstg[8][BC][SSTR];      // per-wave own-slice staging

    const int tid  = threadIdx.x;
    const int lane = tid & 63;
    const int w    = tid >> 6;
    const int wq   = w & 3;
    const int l15  = lane & 15;
    const int l4   = lane >> 4;
    const int koff = 8 * l4;
    const bool sRole = (w < 4);

    const int b = blockIdx.x;
    const int g = b & 15;
    const int p = b >> 4;
    const int row0 = g * BC;

    u32* flags = flags_all + g * 64;
    u32  alive = 1;

    const int c0 = 64 * p + 16 * wq + l15;   // own s/f col (sRole) or u col

    // ---- resident weights -> AGPRs (36 frags = 144 AGPR max) ----
    f32x4 wgt[36];
    {
        const __bf16* rA = (sRole ? W2F : W2M) + (size_t)c0 * MDIM;
        const __bf16* rC = (sRole ? Cm  : Dm ) + (size_t)c0 * FDIM;
        #pragma unroll
        for (int j = 0; j < 16; ++j) {
            wgt[j]      = *(const f32x4*)&rA[j * 32 + koff];
            wgt[16 + j] = *(const f32x4*)&rC[j * 32 + koff];
        }
        if (sRole) {
            const __bf16* rX = WI + (size_t)c0 * IDIM;
            #pragma unroll
            for (int j = 0; j < 4; ++j) wgt[32 + j] = *(const f32x4*)&rX[j * 32 + koff];
        } else {
            #pragma unroll
            for (int j = 32; j < 36; ++j) wgt[j] = f32x4{0, 0, 0, 0};
        }
        #pragma unroll
        for (int j = 0; j < 36; ++j) asm volatile("" : "+a"(wgt[j]));
    }
    const float b1r = sRole ? b1[c0] : 0.f;
    const float cbr = sRole ? cb[c0] : 0.f;
    const float cur = sRole ? 0.f    : cu[c0];

    // ---- prologue: m0 -> ulds, x0 -> xlds; seed accs (epoch-0 pre-state) ----
    #pragma unroll
    for (int i = 0; i < 2; ++i) {
        int c = tid + 512 * i;
        int row = c >> 6, col8 = (c & 63) << 3;
        const float* ms = &m0[(size_t)(row0 + row) * MDIM + col8];
        float4 v0 = ((const float4*)ms)[0], v1 = ((const float4*)ms)[1];
        *(bf16x8*)&ulds[row][col8] =
            bf16x8{(__bf16)v0.x, (__bf16)v0.y, (__bf16)v0.z, (__bf16)v0.w,
                   (__bf16)v1.x, (__bf16)v1.y, (__bf16)v1.z, (__bf16)v1.w};
    }
    if (tid < 256) {
        int rr = tid >> 4, c8 = (tid & 15) << 3;
        const float* xs = &x[(size_t)(row0 + rr) * TLEN * IDIM + c8];
        float4 v0 = ((const float4*)xs)[0], v1 = ((const float4*)xs)[1];
        *(bf16x8*)&xlds[rr][c8] =
            bf16x8{(__bf16)v0.x, (__bf16)v0.y, (__bf16)v0.z, (__bf16)v0.w,
                   (__bf16)v1.x, (__bf16)v1.y, (__bf16)v1.z, (__bf16)v1.w};
    }
    __syncthreads();

    f32x4 accE, accO;                         // s-acc (sRole) / u-acc
    {
        bf16x8 a0 = *(const bf16x8*)&ulds[l15][0 * 32 + koff];
        bf16x8 a1 = *(const bf16x8*)&ulds[l15][1 * 32 + koff];
        mfma_z(accE, a0, wgt[0]);  mfma_z(accO, a1, wgt[1]);
        #pragma unroll
        for (int j = 2; j < 16; ++j) {
            bf16x8 am = *(const bf16x8*)&ulds[l15][j * 32 + koff];
            if (j & 1) mfma_a(accO, am, wgt[j]);
            else       mfma_a(accE, am, wgt[j]);
        }
        if (sRole) {
            #pragma unroll
            for (int j = 0; j < 4; ++j) {
                bf16x8 ax = *(const bf16x8*)&xlds[l15][j * 32 + koff];
                if (j & 1) mfma_a(accO, ax, wgt[32 + j]);
                else       mfma_a(accE, ax, wgt[32 + j]);
            }
        }
    }

    const int erow = lane & 15;               // export row
    const int eq4  = lane >> 4;               // export col-quad

    for (int t = 0; t < TLEN; ++t) {
        // (a) finish state, stage own slice into THIS wave's sstg block
        ACC_GUARD(accE, accO);
        f32x4 va = accE + accO;
        if (sRole) {
            const float addc = (t == 0) ? b1r : cbr;
            #pragma unroll
            for (int r = 0; r < 4; ++r)
                sstg[w][4 * l4 + r][l15] = (__bf16)tanhf(va[r] + addc);
        } else {
            const float addu = (t == 0) ? 0.f : cur;
            #pragma unroll
            for (int r = 0; r < 4; ++r)
                sstg[w][4 * l4 + r][l15] = (__bf16)(va[r] + addu);
        }
        asm volatile("s_waitcnt lgkmcnt(0)" ::: "memory");

        // (b) same-wave export: 1 u64/lane (16x16 slice, coalesced 32B runs)
        const size_t bufbase = (size_t)((t & 1) * NGRP + g) * (2 * BC * MDIM);
        {
            const int mat = sRole ? 1 : 0;    // 0=u, 1=f
            u64 v = *(const u64*)&sstg[w][erow][4 * eq4];
            __bf16* dst = buf + bufbase + (size_t)mat * (BC * MDIM)
                        + erow * MDIM + 64 * p + 16 * wq + 4 * eq4;
            __hip_atomic_store((u64*)dst, v, __ATOMIC_RELAXED, __HIP_MEMORY_SCOPE_AGENT);
        }
        asm volatile("s_waitcnt vmcnt(0)" ::: "memory");
        __syncthreads();                      // barA: all exports drained
        if (tid == 0)
            __hip_atomic_store(&flags[p], (u32)t + 1u,
                               __ATOMIC_RELAXED, __HIP_MEMORY_SCOPE_AGENT);

        // (c) stage x_{t+1} (overlaps the poll RTT)
        if (tid < 256 && t + 1 < TLEN) {
            int rr = tid >> 4, c8 = (tid & 15) << 3;
            const float* xs = &x[((size_t)(row0 + rr) * TLEN + (t + 1)) * IDIM + c8];
            float4 v0 = ((const float4*)xs)[0], v1 = ((const float4*)xs)[1];
            *(bf16x8*)&xlds[rr][c8] =
                bf16x8{(__bf16)v0.x, (__bf16)v0.y, (__bf16)v0.z, (__bf16)v0.w,
                       (__bf16)v1.x, (__bf16)v1.y, (__bf16)v1.z, (__bf16)v1.w};
        }
        poll_flags(flags, (u32)t + 1u, lane, alive);

        // (d) gather full (u_t, f_t): 4 x 16B/thread, coalesced
        #pragma unroll
        for (int i = 0; i < 4; ++i) {
            int c = tid + 512 * i;
            int mat = c >> 10, rem = c & 1023;
            int row = rem >> 6, col8 = (rem & 63) << 3;
            const __bf16* src = buf + bufbase + (size_t)mat * (BC * MDIM)
                              + row * MDIM + col8;
            u64 lo = __hip_atomic_load((const u64*)src,     __ATOMIC_RELAXED, __HIP_MEMORY_SCOPE_AGENT);
            u64 hi = __hip_atomic_load((const u64*)src + 1, __ATOMIC_RELAXED, __HIP_MEMORY_SCOPE_AGENT);
            union { u64 q[2]; bf16x8 v; } uu; uu.q[0] = lo; uu.q[1] = hi;
            if (mat) *(bf16x8*)&flds[row][col8] = uu.v;
            else     *(bf16x8*)&ulds[row][col8] = uu.v;
        }
        __syncthreads();                      // barB: epoch-t (u,f) in LDS

        if (t == TLEN - 1) break;

        // (e) next state: s' = u@W2F + f@C + x@WI ; u' = u@W2M + f@D
        {
            bf16x8 a0 = *(const bf16x8*)&ulds[l15][0 * 32 + koff];
            bf16x8 a1 = *(const bf16x8*)&ulds[l15][1 * 32 + koff];
            mfma_z(accE, a0, wgt[0]);  mfma_z(accO, a1, wgt[1]);
            #pragma unroll
            for (int j = 2; j < 16; ++j) {
                bf16x8 am = *(const bf16x8*)&ulds[l15][j * 32 + koff];
                if (j & 1) mfma_a(accO, am, wgt[j]);
                else       mfma_a(accE, am, wgt[j]);
            }
            #pragma unroll
            for (int j = 0; j < 16; ++j) {
                bf16x8 af = *(const bf16x8*)&flds[l15][j * 32 + koff];
                if (j & 1) mfma_a(accO, af, wgt[16 + j]);
                else       mfma_a(accE, af, wgt[16 + j]);
            }
            if (sRole) {
                #pragma unroll
                for (int j = 0; j < 4; ++j) {
                    bf16x8 ax = *(const bf16x8*)&xlds[l15][j * 32 + koff];
                    if (j & 1) mfma_a(accO, ax, wgt[32 + j]);
                    else       mfma_a(accE, ax, wgt[32 + j]);
                }
            }
        }
    }

    // ---- epilogue (p==0): m_T = u + f@WF2^T + b23; out = m_T@WO^T + bout ----
    if (p == 0) {
        f32x4 ma[4];
        #pragma unroll
        for (int nt = 0; nt < 4; ++nt) {
            int ct = 64 * w + 16 * nt + l15;
            f32x4 acc = {0, 0, 0, 0};
            #pragma unroll
            for (int j = 0; j < 16; ++j) {
                bf16x8 af = *(const bf16x8*)&flds[l15][j * 32 + koff];
                bf16x8 bw = *(const bf16x8*)&WF2[(size_t)ct * FDIM + j * 32 + koff];
                acc = mfma16(af, bw, acc);
            }
            ma[nt] = acc;
        }
        #pragma unroll
        for (int nt = 0; nt < 4; ++nt) {
            int ct = 64 * w + 16 * nt + l15;
            #pragma unroll
            for (int r = 0; r < 4; ++r) {
                float mv = ma[nt][r] + (float)ulds[4 * l4 + r][ct] + b23[ct];
                ulds[4 * l4 + r][ct] = (__bf16)mv;    // own cols only: no race
            }
        }
        __syncthreads();
        const int oc = 16 * w + l15;
        const __bf16* ro = WO + (size_t)oc * MDIM;
        f32x4 oe = {0, 0, 0, 0}, oo = {0, 0, 0, 0};
        #pragma unroll
        for (int j = 0; j < 16; ++j) {
            bf16x8 am = *(const bf16x8*)&ulds[l15][j * 32 + koff];
            bf16x8 bw = *(const bf16x8*)&ro[j * 32 + koff];
            if (j & 1) oo = mfma16(am, bw, oo); else oe = mfma16(am, bw, oe);
        }
        f32x4 oa = oe + oo;
        const float bo = bout[oc];
        #pragma unroll
        for (int r = 0; r < 4; ++r)
            out[(size_t)(row0 + 4 * l4 + r) * ODIM + oc] = oa[r] + bo;
    }
}

extern "C" void kernel_launch(void* const* d_in, const int* in_sizes, int n_in,
                              void* d_out, int out_size, void* d_ws, size_t ws_size,
                              hipStream_t stream)
{
    const float* x    = (const float*)d_in[0];
    const float* m0   = (const float*)d_in[1];
    const float* Wi2f = (const float*)d_in[2];
    const float* bi2f = (const float*)d_in[3];
    const float* Wm2f = (const float*)d_in[4];
    const float* bm2f = (const float*)d_in[5];
    const float* Wf2m = (const float*)d_in[6];
    const float* bf2m = (const float*)d_in[7];
    const float* Wm2m = (const float*)d_in[8];
    const float* bm2m = (const float*)d_in[9];
    const float* Wout = (const float*)d_in[10];
    const float* bout = (const float*)d_in[11];

    char* ws = (char*)d_ws;
    __bf16* WI  = (__bf16*)(ws + WS_WI);
    __bf16* W2F = (__bf16*)(ws + WS_W2F);
    __bf16* W2M = (__bf16*)(ws + WS_W2M);
    __bf16* WF2 = (__bf16*)(ws + WS_WF2);
    __bf16* WO  = (__bf16*)(ws + WS_WO);
    __bf16* Cm  = (__bf16*)(ws + WS_C);
    __bf16* Dm  = (__bf16*)(ws + WS_D);
    float*  b1  = (float*)(ws + WS_B1);
    float*  b23 = (float*)(ws + WS_B23);
    float*  cb  = (float*)(ws + WS_CB);
    float*  cu  = (float*)(ws + WS_CU);
    u32*    flg = (u32*)(ws + WS_FLG);
    __bf16* buf = (__bf16*)(ws + WS_BUF);

    const int prep1_total = N_WI + N_W2F + N_W2M + N_WF2 + N_WO
                          + FDIM + MDIM + NGRP * 64;
    lmn_prep1<<<(prep1_total + 255) / 256, 256, 0, stream>>>(
        Wi2f, Wm2f, Wm2m, Wf2m, Wout, bi2f, bm2f, bf2m, bm2m,
        WI, W2F, W2M, WF2, WO, b1, b23, flg);

    lmn_prep2<<<2052, 256, 0, stream>>>(Wm2f, Wm2m, Wf2m, b1, b23, Cm, Dm, cb, cu);

    lmn_scan<<<NGRP * NCU, 512, 0, stream>>>(
        x, m0, WI, W2F, W2M, Cm, Dm, WF2, WO,
        b1, cb, cu, b23, bout, flg, buf, (float*)d_out);
}

// Round 16
// 1537.283 us; speedup vs baseline: 2.1399x; 1.2056x over previous
//
#include <hip/hip_runtime.h>
#include <hip/hip_bf16.h>

typedef __bf16 bf16x8 __attribute__((ext_vector_type(8)));
typedef __bf16 bf16x4 __attribute__((ext_vector_type(4)));
typedef float  f32x4  __attribute__((ext_vector_type(4)));
typedef unsigned int u32;
typedef unsigned long long u64;

// ---- inline-asm MFMA with B operand in AGPR (proven R7/R13/R15) ----------
static __device__ __forceinline__ void mfma_z(f32x4& d, bf16x8 a, const f32x4& b) {
    asm("v_mfma_f32_16x16x32_bf16 %0, %1, %2, 0"
        : "=&v"(d) : "v"(a), "a"(b));
}
static __device__ __forceinline__ void mfma_a(f32x4& d, bf16x8 a, const f32x4& b) {
    asm("v_mfma_f32_16x16x32_bf16 %0, %1, %2, %0"
        : "+v"(d) : "v"(a), "a"(b));
}
#define ACC_GUARD(e, o) asm volatile("s_nop 7\n\ts_nop 7" : "+v"(e), "+v"(o))

static __device__ __forceinline__ f32x4 mfma16(bf16x8 a, bf16x8 b, f32x4 c) {
    return __builtin_amdgcn_mfma_f32_16x16x32_bf16(a, b, c, 0, 0, 0);
}

// Tight bounded spin + give-up latch (protocol failure -> fast absmax FAIL)
static __device__ __forceinline__ void poll_flags(const u32* flags, u32 tgt,
                                                  int lane, u32& alive) {
    if (!alive) return;
    for (u32 it = 0; it < (1u << 22); ++it) {
        u32 v = __hip_atomic_load(&flags[lane & 7], __ATOMIC_RELAXED, __HIP_MEMORY_SCOPE_AGENT);
        if (__all((int)(v >= tgt))) return;
    }
    alive = 0;
}

#define TLEN 512
#define IDIM 128
#define FDIM 512
#define MDIM 512
#define ODIM 128
#define BC   8       // batch rows per group (32 groups -> all 256 CUs)
#define NGRP 32
#define NCU  8
#define PSTR 520
#define XSTR 136
#define SSTR 24      // sstg row stride: 48B -> 16B-aligned bf16x8 reads

// ---- ws byte offsets ----
#define WS_WI   0                               // bf16 [512][128]
#define WS_W2F  (WS_WI  + FDIM*IDIM*2)          // bf16 [512][512] (Wm2f)
#define WS_W2M  (WS_W2F + FDIM*MDIM*2)          // bf16 [512][512] (Wm2m)
#define WS_WF2  (WS_W2M + MDIM*MDIM*2)          // bf16 [512][512] (Wf2m)
#define WS_WO   (WS_WF2 + MDIM*FDIM*2)          // bf16 [128][512]
#define WS_C    (WS_WO  + ODIM*MDIM*2)          // bf16 [512][512] = Wm2f@Wf2m
#define WS_D    (WS_C   + FDIM*FDIM*2)          // bf16 [512][512] = Wm2m@Wf2m
#define WS_B1   (WS_D   + MDIM*FDIM*2)          // f32 512
#define WS_B23  (WS_B1  + FDIM*4)               // f32 512
#define WS_CB   (WS_B23 + MDIM*4)               // f32 512: b1 + Wm2f@b23
#define WS_CU   (WS_CB  + FDIM*4)               // f32 512: Wm2m@b23
#define WS_FLG  (WS_CU  + MDIM*4)               // u32 [NGRP][64]
#define WS_BUF  (WS_FLG + NGRP*64*4)            // bf16 [2][NGRP][2][8][512] = 1MB

#define N_WI  (FDIM*IDIM)
#define N_W2F (FDIM*MDIM)
#define N_W2M (MDIM*MDIM)
#define N_WF2 (MDIM*FDIM)
#define N_WO  (ODIM*MDIM)

__global__ __launch_bounds__(256) void lmn_prep1(
    const float* __restrict__ Wi2f, const float* __restrict__ Wm2f,
    const float* __restrict__ Wm2m, const float* __restrict__ Wf2m,
    const float* __restrict__ Wout,
    const float* __restrict__ bi2f, const float* __restrict__ bm2f,
    const float* __restrict__ bf2m, const float* __restrict__ bm2m,
    __bf16* __restrict__ WI, __bf16* __restrict__ W2F, __bf16* __restrict__ W2M,
    __bf16* __restrict__ WF2, __bf16* __restrict__ WO,
    float* __restrict__ b1, float* __restrict__ b23, u32* __restrict__ flags)
{
    int i = blockIdx.x * 256 + threadIdx.x;
    if (i < N_WI)  { WI[i]  = (__bf16)Wi2f[i]; return; }  i -= N_WI;
    if (i < N_W2F) { W2F[i] = (__bf16)Wm2f[i]; return; }  i -= N_W2F;
    if (i < N_W2M) { W2M[i] = (__bf16)Wm2m[i]; return; }  i -= N_W2M;
    if (i < N_WF2) { WF2[i] = (__bf16)Wf2m[i]; return; }  i -= N_WF2;
    if (i < N_WO)  { WO[i]  = (__bf16)Wout[i]; return; }  i -= N_WO;
    if (i < FDIM)  { b1[i]  = bi2f[i] + bm2f[i]; return; } i -= FDIM;
    if (i < MDIM)  { b23[i] = bf2m[i] + bm2m[i]; return; } i -= MDIM;
    if (i < NGRP * 64) { flags[i] = 0u; return; }
}

// Composites: C = Wm2f@Wf2m, D = Wm2m@Wf2m, cb = b1 + Wm2f@b23, cu = Wm2m@b23
__global__ __launch_bounds__(256) void lmn_prep2(
    const float* __restrict__ Wm2f, const float* __restrict__ Wm2m,
    const float* __restrict__ Wf2m,
    const float* __restrict__ b1, const float* __restrict__ b23,
    __bf16* __restrict__ C, __bf16* __restrict__ D,
    float* __restrict__ cb, float* __restrict__ cu)
{
    int bb = blockIdx.x;
    if (bb < 2048) {
        int row = bb >> 1;
        int k   = (bb & 1) * 256 + threadIdx.x;
        const float* A = (row < 512) ? Wm2f : Wm2m;
        int r = row & 511;
        float acc = 0.f;
        for (int j = 0; j < 512; ++j)
            acc += A[(size_t)r * 512 + j] * Wf2m[(size_t)j * 512 + k];
        if (row < 512) C[(size_t)r * 512 + k] = (__bf16)acc;
        else           D[(size_t)r * 512 + k] = (__bf16)acc;
        return;
    }
    int idx = (bb - 2048) * 256 + threadIdx.x;
    if (idx < 512) {
        float acc = b1[idx];
        for (int j = 0; j < 512; ++j) acc += Wm2f[(size_t)idx * 512 + j] * b23[j];
        cb[idx] = acc;
    } else {
        int r = idx - 512;
        float acc = 0.f;
        for (int j = 0; j < 512; ++j) acc += Wm2m[(size_t)r * 512 + j] * b23[j];
        cu[r] = acc;
    }
}

// ---------------------------------------------------------------------------
// R15 state-transformed scan, all 256 CUs: BC=8 rows/group, 32 groups.
// Exchange per step: export 2 KB/WG, gather 16 KB/WG (half of R15) -- the
// gather is the dependent post-poll load on the critical path. A-fragment
// rows duplicate (ar = l15&7): same-address LDS broadcast, outputs of rows
// 8-15 discarded. Weights rotated so own k-frags are j=0,1: their 4 MFMA
// run from sstg right after barA, inside the poll window. Protocol,
// overwrite gating, give-up latch identical to R13/R15 (validated).
// ---------------------------------------------------------------------------
__global__ __launch_bounds__(512, 2) void lmn_scan(
    const float* __restrict__ x, const float* __restrict__ m0,
    const __bf16* __restrict__ WI, const __bf16* __restrict__ W2F,
    const __bf16* __restrict__ W2M, const __bf16* __restrict__ Cm,
    const __bf16* __restrict__ Dm, const __bf16* __restrict__ WF2,
    const __bf16* __restrict__ WO,
    const float* __restrict__ b1, const float* __restrict__ cb,
    const float* __restrict__ cu, const float* __restrict__ b23,
    const float* __restrict__ bout,
    u32* __restrict__ flags_all, __bf16* __restrict__ buf,
    float* __restrict__ out)
{
    __shared__ __bf16 ulds[BC][PSTR];
    __shared__ __bf16 flds[BC][PSTR];
    __shared__ __bf16 xlds[BC][XSTR];
    __shared__ __bf16 sstg[8][BC][SSTR];      // per-wave own-slice staging

    const int tid  = threadIdx.x;
    const int lane = tid & 63;
    const int w    = tid >> 6;
    const int wq   = w & 3;
    const int l15  = lane & 15;
    const int l4   = lane >> 4;
    const int koff = 8 * l4;
    const int ar   = l15 & 7;                 // A-row (8 valid rows, dup)
    const bool sRole = (w < 4);

    const int b = blockIdx.x;
    const int g = b & 31;
    const int p = b >> 5;
    const int row0 = g * BC;

    u32* flags = flags_all + g * 64;
    u32  alive = 1;

    const int c0 = 64 * p + 16 * wq + l15;    // own s/f col (sRole) or u col

    // ---- resident weights -> AGPRs, rotated so own k-frags are j=0,1 ----
    f32x4 wgt[36];
    {
        const __bf16* rA = (sRole ? W2F : W2M) + (size_t)c0 * MDIM;
        const __bf16* rC = (sRole ? Cm  : Dm ) + (size_t)c0 * FDIM;
        #pragma unroll
        for (int j = 0; j < 16; ++j) {
            int kk = (2 * p + j) & 15;
            wgt[j]      = *(const f32x4*)&rA[kk * 32 + koff];
            wgt[16 + j] = *(const f32x4*)&rC[kk * 32 + koff];
        }
        if (sRole) {
            const __bf16* rX = WI + (size_t)c0 * IDIM;
            #pragma unroll
            for (int j = 0; j < 4; ++j) wgt[32 + j] = *(const f32x4*)&rX[j * 32 + koff];
        } else {
            #pragma unroll
            for (int j = 32; j < 36; ++j) wgt[j] = f32x4{0, 0, 0, 0};
        }
        #pragma unroll
        for (int j = 0; j < 36; ++j) asm volatile("" : "+a"(wgt[j]));
    }
    const float b1r = sRole ? b1[c0] : 0.f;
    const float cbr = sRole ? cb[c0] : 0.f;
    const float cur = sRole ? 0.f    : cu[c0];

    // ---- prologue: m0 -> ulds, x0 -> xlds; seed epoch-0 accs ----
    {
        int row = tid >> 6, col8 = (tid & 63) << 3;   // 512 chunks = 8x512
        const float* ms = &m0[(size_t)(row0 + row) * MDIM + col8];
        float4 v0 = ((const float4*)ms)[0], v1 = ((const float4*)ms)[1];
        *(bf16x8*)&ulds[row][col8] =
            bf16x8{(__bf16)v0.x, (__bf16)v0.y, (__bf16)v0.z, (__bf16)v0.w,
                   (__bf16)v1.x, (__bf16)v1.y, (__bf16)v1.z, (__bf16)v1.w};
    }
    if (tid < 128) {
        int rr = tid >> 4, c8 = (tid & 15) << 3;
        const float* xs = &x[(size_t)(row0 + rr) * TLEN * IDIM + c8];
        float4 v0 = ((const float4*)xs)[0], v1 = ((const float4*)xs)[1];
        *(bf16x8*)&xlds[rr][c8] =
            bf16x8{(__bf16)v0.x, (__bf16)v0.y, (__bf16)v0.z, (__bf16)v0.w,
                   (__bf16)v1.x, (__bf16)v1.y, (__bf16)v1.z, (__bf16)v1.w};
    }
    __syncthreads();

    f32x4 accE, accO;                         // s-acc (sRole) / u-acc
    {
        bf16x8 a0 = *(const bf16x8*)&ulds[ar][((2 * p + 0) & 15) * 32 + koff];
        bf16x8 a1 = *(const bf16x8*)&ulds[ar][((2 * p + 1) & 15) * 32 + koff];
        mfma_z(accE, a0, wgt[0]);  mfma_z(accO, a1, wgt[1]);
        #pragma unroll
        for (int j = 2; j < 16; ++j) {
            bf16x8 am = *(const bf16x8*)&ulds[ar][((2 * p + j) & 15) * 32 + koff];
            if (j & 1) mfma_a(accO, am, wgt[j]);
            else       mfma_a(accE, am, wgt[j]);
        }
        if (sRole) {
            #pragma unroll
            for (int j = 0; j < 4; ++j) {
                bf16x8 ax = *(const bf16x8*)&xlds[ar][j * 32 + koff];
                if (j & 1) mfma_a(accO, ax, wgt[32 + j]);
                else       mfma_a(accE, ax, wgt[32 + j]);
            }
        }
    }

    for (int t = 0; t < TLEN; ++t) {
        // (a) finish epoch-t state, stage own slice (rows 0..7 only)
        ACC_GUARD(accE, accO);
        f32x4 va = accE + accO;
        if (l4 < 2) {
            if (sRole) {
                const float addc = (t == 0) ? b1r : cbr;
                #pragma unroll
                for (int r = 0; r < 4; ++r)
                    sstg[w][4 * l4 + r][l15] = (__bf16)tanhf(va[r] + addc);
            } else {
                const float addu = (t == 0) ? 0.f : cur;
                #pragma unroll
                for (int r = 0; r < 4; ++r)
                    sstg[w][4 * l4 + r][l15] = (__bf16)(va[r] + addu);
            }
        }
        asm volatile("s_waitcnt lgkmcnt(0)" ::: "memory");

        // (b) same-wave export: lanes 0..31, 1 u64 each (8 rows x 16 cols)
        const size_t bufbase = (size_t)((t & 1) * NGRP + g) * (2 * BC * MDIM);
        if (lane < 32) {
            const int mat  = sRole ? 1 : 0;   // 0=u, 1=f
            const int erow = lane & 7, eq = lane >> 3;
            u64 v = *(const u64*)&sstg[w][erow][4 * eq];
            __bf16* dst = buf + bufbase + (size_t)mat * (BC * MDIM)
                        + erow * MDIM + 64 * p + 16 * wq + 4 * eq;
            __hip_atomic_store((u64*)dst, v, __ATOMIC_RELAXED, __HIP_MEMORY_SCOPE_AGENT);
        }
        asm volatile("s_waitcnt vmcnt(0)" ::: "memory");
        __syncthreads();                      // barA: exports drained, sstg visible
        if (tid == 0)
            __hip_atomic_store(&flags[p], (u32)t + 1u,
                               __ATOMIC_RELAXED, __HIP_MEMORY_SCOPE_AGENT);

        // (early) own-block MFMA for epoch t+1 from sstg (inside poll window)
        if (t + 1 < TLEN) {
            const int cc = 8 * (l4 & 1);
            bf16x8 au0 = *(const bf16x8*)&sstg[4 + (l4 >> 1)][ar][cc];
            bf16x8 au1 = *(const bf16x8*)&sstg[6 + (l4 >> 1)][ar][cc];
            bf16x8 af0 = *(const bf16x8*)&sstg[0 + (l4 >> 1)][ar][cc];
            bf16x8 af1 = *(const bf16x8*)&sstg[2 + (l4 >> 1)][ar][cc];
            mfma_z(accE, au0, wgt[0]);   mfma_z(accO, au1, wgt[1]);
            mfma_a(accE, af0, wgt[16]);  mfma_a(accO, af1, wgt[17]);
        }

        // (c) stage x_{t+1} (overlaps poll RTT)
        if (tid < 128 && t + 1 < TLEN) {
            int rr = tid >> 4, c8 = (tid & 15) << 3;
            const float* xs = &x[((size_t)(row0 + rr) * TLEN + (t + 1)) * IDIM + c8];
            float4 v0 = ((const float4*)xs)[0], v1 = ((const float4*)xs)[1];
            *(bf16x8*)&xlds[rr][c8] =
                bf16x8{(__bf16)v0.x, (__bf16)v0.y, (__bf16)v0.z, (__bf16)v0.w,
                       (__bf16)v1.x, (__bf16)v1.y, (__bf16)v1.z, (__bf16)v1.w};
        }
        poll_flags(flags, (u32)t + 1u, lane, alive);

        // (d) gather full (u_t, f_t): 2 x 16B per thread (16 KB total)
        {
            int mat = tid >> 8, rem = tid & 255;
            int row = rem >> 5, col16 = (rem & 31) << 4;
            const __bf16* src = buf + bufbase + (size_t)mat * (BC * MDIM)
                              + row * MDIM + col16;
            u64 q0 = __hip_atomic_load((const u64*)src,     __ATOMIC_RELAXED, __HIP_MEMORY_SCOPE_AGENT);
            u64 q1 = __hip_atomic_load((const u64*)src + 1, __ATOMIC_RELAXED, __HIP_MEMORY_SCOPE_AGENT);
            u64 q2 = __hip_atomic_load((const u64*)src + 2, __ATOMIC_RELAXED, __HIP_MEMORY_SCOPE_AGENT);
            u64 q3 = __hip_atomic_load((const u64*)src + 3, __ATOMIC_RELAXED, __HIP_MEMORY_SCOPE_AGENT);
            __bf16* dl = mat ? &flds[row][col16] : &ulds[row][col16];
            ((u64*)dl)[0] = q0; ((u64*)dl)[1] = q1;
            ((u64*)dl)[2] = q2; ((u64*)dl)[3] = q3;
        }
        __syncthreads();                      // barB: epoch-t (u,f) in LDS

        if (t == TLEN - 1) break;

        // (e) remaining frags: u j=2..15, f j=2..15, x j=0..3 (sRole)
        {
            #pragma unroll
            for (int j = 2; j < 16; ++j) {
                bf16x8 am = *(const bf16x8*)&ulds[ar][((2 * p + j) & 15) * 32 + koff];
                if (j & 1) mfma_a(accO, am, wgt[j]);
                else       mfma_a(accE, am, wgt[j]);
            }
            #pragma unroll
            for (int j = 2; j < 16; ++j) {
                bf16x8 af = *(const bf16x8*)&flds[ar][((2 * p + j) & 15) * 32 + koff];
                if (j & 1) mfma_a(accO, af, wgt[16 + j]);
                else       mfma_a(accE, af, wgt[16 + j]);
            }
            if (sRole) {
                #pragma unroll
                for (int j = 0; j < 4; ++j) {
                    bf16x8 ax = *(const bf16x8*)&xlds[ar][j * 32 + koff];
                    if (j & 1) mfma_a(accO, ax, wgt[32 + j]);
                    else       mfma_a(accE, ax, wgt[32 + j]);
                }
            }
        }
    }

    // ---- epilogue (p==0): m_T = u + f@WF2^T + b23; out = m_T@WO^T + bout ----
    if (p == 0) {
        f32x4 ma[4];
        #pragma unroll
        for (int nt = 0; nt < 4; ++nt) {
            int ct = 64 * w + 16 * nt + l15;
            f32x4 acc = {0, 0, 0, 0};
            #pragma unroll
            for (int j = 0; j < 16; ++j) {
                bf16x8 af = *(const bf16x8*)&flds[ar][j * 32 + koff];
                bf16x8 bw = *(const bf16x8*)&WF2[(size_t)ct * FDIM + j * 32 + koff];
                acc = mfma16(af, bw, acc);
            }
            ma[nt] = acc;
        }
        #pragma unroll
        for (int nt = 0; nt < 4; ++nt) {
            int ct = 64 * w + 16 * nt + l15;
            if (l4 < 2) {
                #pragma unroll
                for (int r = 0; r < 4; ++r) {
                    int rr = 4 * l4 + r;
                    float mv = ma[nt][r] + (float)ulds[rr][ct] + b23[ct];
                    ulds[rr][ct] = (__bf16)mv;    // own cols only: no race
                }
            }
        }
        __syncthreads();
        const int oc = 16 * w + l15;
        const __bf16* ro = WO + (size_t)oc * MDIM;
        f32x4 oe = {0, 0, 0, 0}, oo = {0, 0, 0, 0};
        #pragma unroll
        for (int j = 0; j < 16; ++j) {
            bf16x8 am = *(const bf16x8*)&ulds[ar][j * 32 + koff];
            bf16x8 bw = *(const bf16x8*)&ro[j * 32 + koff];
            if (j & 1) oo = mfma16(am, bw, oo); else oe = mfma16(am, bw, oe);
        }
        f32x4 oa = oe + oo;
        const float bo = bout[oc];
        if (l4 < 2) {
            #pragma unroll
            for (int r = 0; r < 4; ++r) {
                int rr = 4 * l4 + r;
                out[(size_t)(row0 + rr) * ODIM + oc] = oa[r] + bo;
            }
        }
    }
}

extern "C" void kernel_launch(void* const* d_in, const int* in_sizes, int n_in,
                              void* d_out, int out_size, void* d_ws, size_t ws_size,
                              hipStream_t stream)
{
    const float* x    = (const float*)d_in[0];
    const float* m0   = (const float*)d_in[1];
    const float* Wi2f = (const float*)d_in[2];
    const float* bi2f = (const float*)d_in[3];
    const float* Wm2f = (const float*)d_in[4];
    const float* bm2f = (const float*)d_in[5];
    const float* Wf2m = (const float*)d_in[6];
    const float* bf2m = (const float*)d_in[7];
    const float* Wm2m = (const float*)d_in[8];
    const float* bm2m = (const float*)d_in[9];
    const float* Wout = (const float*)d_in[10];
    const float* bout = (const float*)d_in[11];

    char* ws = (char*)d_ws;
    __bf16* WI  = (__bf16*)(ws + WS_WI);
    __bf16* W2F = (__bf16*)(ws + WS_W2F);
    __bf16* W2M = (__bf16*)(ws + WS_W2M);
    __bf16* WF2 = (__bf16*)(ws + WS_WF2);
    __bf16* WO  = (__bf16*)(ws + WS_WO);
    __bf16* Cm  = (__bf16*)(ws + WS_C);
    __bf16* Dm  = (__bf16*)(ws + WS_D);
    float*  b1  = (float*)(ws + WS_B1);
    float*  b23 = (float*)(ws + WS_B23);
    float*  cb  = (float*)(ws + WS_CB);
    float*  cu  = (float*)(ws + WS_CU);
    u32*    flg = (u32*)(ws + WS_FLG);
    __bf16* buf = (__bf16*)(ws + WS_BUF);

    const int prep1_total = N_WI + N_W2F + N_W2M + N_WF2 + N_WO
                          + FDIM + MDIM + NGRP * 64;
    lmn_prep1<<<(prep1_total + 255) / 256, 256, 0, stream>>>(
        Wi2f, Wm2f, Wm2m, Wf2m, Wout, bi2f, bm2f, bf2m, bm2m,
        WI, W2F, W2M, WF2, WO, b1, b23, flg);

    lmn_prep2<<<2052, 256, 0, stream>>>(Wm2f, Wm2m, Wf2m, b1, b23, Cm, Dm, cb, cu);

    lmn_scan<<<NGRP * NCU, 512, 0, stream>>>(
        x, m0, WI, W2F, W2M, Cm, Dm, WF2, WO,
        b1, cb, cu, b23, bout, flg, buf, (float*)d_out);
}